// Round 1
// baseline (201.113 us; speedup 1.0000x reference)
//
#include <hip/hip_runtime.h>
#include <hip/hip_bf16.h>

typedef __bf16 bf16_t;
typedef __bf16 bf16x8 __attribute__((ext_vector_type(8)));
typedef __bf16 bf16x4 __attribute__((ext_vector_type(4)));
typedef float  f32x4  __attribute__((ext_vector_type(4)));

#define LN_EPS 1e-5f

// Problem sizes (fixed by the reference)
//  B=8, T=512, C=768 -> M = B*T = 4096, 4C = 3072

// ---------------- fp32 -> bf16 conversion (vectorized x4) ----------------
__global__ __launch_bounds__(256) void k_cvt_bf16(const float* __restrict__ src,
                                                  bf16_t* __restrict__ dst, int n4) {
    int i = blockIdx.x * 256 + threadIdx.x;
    if (i < n4) {
        float4 v = ((const float4*)src)[i];
        bf16x4 o;
        o.x = (bf16_t)v.x; o.y = (bf16_t)v.y; o.z = (bf16_t)v.z; o.w = (bf16_t)v.w;
        ((bf16x4*)dst)[i] = o;
    }
}

// ---------------- LayerNorm (one block per row of C=768), bf16 out ----------------
__global__ __launch_bounds__(256) void k_ln(const float* __restrict__ x,
                                            const float* __restrict__ w,
                                            const float* __restrict__ b,
                                            bf16_t* __restrict__ out, int C) {
    int row = blockIdx.x;
    const float* xr = x + (long)row * C;
    int tid = threadIdx.x;
    float s = 0.f, s2 = 0.f;
    for (int i = tid; i < C; i += 256) { float v = xr[i]; s += v; s2 += v * v; }
    // wave64 butterfly reduce
    for (int m = 32; m; m >>= 1) { s += __shfl_xor(s, m, 64); s2 += __shfl_xor(s2, m, 64); }
    __shared__ float red[8];
    int wv = tid >> 6;
    if ((tid & 63) == 0) { red[wv] = s; red[4 + wv] = s2; }
    __syncthreads();
    float ts  = red[0] + red[1] + red[2] + red[3];
    float ts2 = red[4] + red[5] + red[6] + red[7];
    float mu  = ts / C;
    float var = ts2 / C - mu * mu;
    float rstd = rsqrtf(var + LN_EPS);
    bf16_t* orow = out + (long)row * C;
    for (int i = tid; i < C; i += 256)
        orow[i] = (bf16_t)((xr[i] - mu) * rstd * w[i] + b[i]);
}

// ---------------- bf16 MFMA GEMM:  C[M][N] = A[M][K] * Bw[N][K]^T ----------------
// 128x128 tile, 4 waves (2x2 of 64x64), 16x16x32 bf16 MFMA, BK=32.
// EPI 0: store fp32          EPI 1: store bf16(relu(x)^2)      EPI 2: store fp32 aux+val
template <int EPI>
__global__ __launch_bounds__(256) void k_gemm_bt(const bf16_t* __restrict__ A,
                                                 const bf16_t* __restrict__ Bw,
                                                 void* __restrict__ Cout,
                                                 const float* __restrict__ aux,
                                                 int N, int K) {
    // +8 bf16 pad (16B) keeps 16B alignment, breaks bank-conflict stride
    __shared__ __align__(16) bf16_t As[128][40];
    __shared__ __align__(16) bf16_t Bs[128][40];
    const int tid  = threadIdx.x;
    const int lane = tid & 63, wid = tid >> 6;
    const int wm = (wid >> 1) * 64, wn = (wid & 1) * 64;
    const int bm = blockIdx.y, bn = blockIdx.x;
    const int arow = tid >> 2, acol = (tid & 3) * 8;   // staging: 2 rows x 1 vec8 each
    const int fr = lane & 15, ko = (lane >> 4) * 8;    // fragment row / k-octet

    f32x4 acc[4][4];
#pragma unroll
    for (int i = 0; i < 4; i++)
#pragma unroll
        for (int j = 0; j < 4; j++) acc[i][j] = (f32x4){0.f, 0.f, 0.f, 0.f};

    const bf16_t* Ag = A  + (long)(bm * 128 + arow) * K + acol;
    const bf16_t* Bg = Bw + (long)(bn * 128 + arow) * K + acol;

    for (int kt = 0; kt < K; kt += 32) {
        __syncthreads();
        *(uint4*)&As[arow][acol]      = *(const uint4*)(Ag + kt);
        *(uint4*)&As[arow + 64][acol] = *(const uint4*)(Ag + (long)64 * K + kt);
        *(uint4*)&Bs[arow][acol]      = *(const uint4*)(Bg + kt);
        *(uint4*)&Bs[arow + 64][acol] = *(const uint4*)(Bg + (long)64 * K + kt);
        __syncthreads();
        bf16x8 af[4], bfr[4];
#pragma unroll
        for (int mi = 0; mi < 4; mi++) af[mi]  = *(const bf16x8*)&As[wm + mi * 16 + fr][ko];
#pragma unroll
        for (int ni = 0; ni < 4; ni++) bfr[ni] = *(const bf16x8*)&Bs[wn + ni * 16 + fr][ko];
#pragma unroll
        for (int mi = 0; mi < 4; mi++)
#pragma unroll
            for (int ni = 0; ni < 4; ni++)
                acc[mi][ni] = __builtin_amdgcn_mfma_f32_16x16x32_bf16(af[mi], bfr[ni], acc[mi][ni], 0, 0, 0);
    }

    const int row0 = bm * 128 + wm, col0 = bn * 128 + wn;
#pragma unroll
    for (int mi = 0; mi < 4; mi++) {
#pragma unroll
        for (int ni = 0; ni < 4; ni++) {
            int row = row0 + mi * 16 + (lane >> 4) * 4;   // C/D: col=lane&15, row=(lane>>4)*4+r
            int col = col0 + ni * 16 + (lane & 15);
#pragma unroll
            for (int r = 0; r < 4; r++) {
                float val = acc[mi][ni][r];
                long off = (long)(row + r) * N + col;
                if (EPI == 0) {
                    ((float*)Cout)[off] = val;
                } else if (EPI == 1) {
                    float t = fmaxf(val, 0.f);
                    ((bf16_t*)Cout)[off] = (bf16_t)(t * t);
                } else {
                    ((float*)Cout)[off] = aux[off] + val;
                }
            }
        }
    }
}

// ---------------- WKV chunked scan ----------------
// y4 layout per (b,t): [ r(768) | k(768) | v(768) | router(768) ]
// Local scan within chunks of L=32 (16 chunks over T=512).
__global__ __launch_bounds__(256) void k_scan_local(const float* __restrict__ y4,
                                                    const float* __restrict__ tmw,
                                                    float* __restrict__ wkvl,
                                                    float* __restrict__ states) {
    int idx = blockIdx.x * 256 + threadIdx.x;  // (b*16 + ch)*768 + c ; total 8*16*768
    int c   = idx % 768;
    int rem = idx / 768;
    int ch  = rem & 15;
    int b   = rem >> 4;
    float d = expf(-expf(tmw[c]));
    const float* base = y4 + ((long)(b * 512 + ch * 32)) * 3072 + c;
    float*       wout = wkvl + ((long)(b * 512 + ch * 32)) * 768 + c;
    float s = 0.f;
#pragma unroll 4
    for (int i = 0; i < 32; i++) {
        float kk = base[(long)i * 3072 + 768];
        float vv = base[(long)i * 3072 + 1536];
        s = s * d + kk * vv;
        wout[(long)i * 768] = s;
    }
    states[idx] = s;
}

__global__ __launch_bounds__(256) void k_scan_carry(const float* __restrict__ states,
                                                    const float* __restrict__ tmw,
                                                    float* __restrict__ carries) {
    int idx = blockIdx.x * 256 + threadIdx.x;  // b*768 + c ; total 8*768
    int c = idx % 768, b = idx / 768;
    float w  = -expf(tmw[c]);
    float dL = expf(w * 32.f);
    float s = 0.f;
    for (int ch = 0; ch < 16; ch++) {
        long o = ((long)(b * 16 + ch)) * 768 + c;
        carries[o] = s;
        s = s * dL + states[o];
    }
}

// x1 = x + r * ( (wkv_local + carry*d^(tmod+1)) * sigmoid(router) )   -- vectorized x4
__global__ __launch_bounds__(256) void k_mix(const float* __restrict__ y4,
                                             const float* __restrict__ wkvl,
                                             const float* __restrict__ carries,
                                             const float* __restrict__ tmw,
                                             const float* __restrict__ x,
                                             float* __restrict__ x1) {
    int idx = blockIdx.x * 256 + threadIdx.x;  // vec4 over 8*512*768
    int e  = idx * 4;
    int c  = e % 768;
    int bt = e / 768;          // b*512 + t
    int t  = bt & 511;
    int b  = bt >> 9;
    float4 wl = *(const float4*)&wkvl[(long)bt * 768 + c];
    float4 cr = *(const float4*)&carries[((long)(b * 16) + (t >> 5)) * 768 + c];
    const float* yrow = y4 + (long)bt * 3072 + c;
    float4 rr = *(const float4*)&yrow[0];
    float4 gg = *(const float4*)&yrow[2304];
    float4 xv = *(const float4*)&x[(long)bt * 768 + c];
    float4 tw = *(const float4*)&tmw[c];
    float tn = (float)((t & 31) + 1);
    float4 o;
    o.x = fmaf(rr.x, (wl.x + cr.x * expf(-expf(tw.x) * tn)) / (1.f + expf(-gg.x)), xv.x);
    o.y = fmaf(rr.y, (wl.y + cr.y * expf(-expf(tw.y) * tn)) / (1.f + expf(-gg.y)), xv.y);
    o.z = fmaf(rr.z, (wl.z + cr.z * expf(-expf(tw.z) * tn)) / (1.f + expf(-gg.z)), xv.z);
    o.w = fmaf(rr.w, (wl.w + cr.w * expf(-expf(tw.w) * tn)) / (1.f + expf(-gg.w)), xv.w);
    *(float4*)&x1[(long)bt * 768 + c] = o;
}

// ---------------- host-side launch ----------------
extern "C" void kernel_launch(void* const* d_in, const int* in_sizes, int n_in,
                              void* d_out, int out_size, void* d_ws, size_t ws_size,
                              hipStream_t stream) {
    const float* x    = (const float*)d_in[0];
    const float* ln1w = (const float*)d_in[1];
    const float* ln1b = (const float*)d_in[2];
    const float* Wr   = (const float*)d_in[3];
    const float* Wk   = (const float*)d_in[4];
    const float* Wv   = (const float*)d_in[5];
    const float* tmw  = (const float*)d_in[6];
    const float* Wrt  = (const float*)d_in[7];
    const float* ln2w = (const float*)d_in[8];
    const float* ln2b = (const float*)d_in[9];
    const float* Wck  = (const float*)d_in[10];
    const float* Wcv  = (const float*)d_in[11];
    float* out = (float*)d_out;
    char* ws = (char*)d_ws;

    // workspace layout (bytes)
    bf16_t* xx     = (bf16_t*)(ws + 0);          //  4096*768  bf16  (xx, later xx2)
    bf16_t* wcat   = (bf16_t*)(ws + 6291456);    //  [4][768][768] bf16 (r,k,v,router)
    bf16_t* wckb   = (bf16_t*)(ws + 11010048);   //  [3072][768] bf16
    bf16_t* wcvb   = (bf16_t*)(ws + 15728640);   //  [768][3072] bf16
    float*  y4     = (float*)(ws + 20447232);    //  [4096][3072] fp32
    bf16_t* kcm    = (bf16_t*)(ws + 20447232);   //  [4096][3072] bf16 (reuses y4 after mix)
    float*  wkvl   = (float*)(ws + 70778880);    //  [4096][768] fp32
    float*  states = (float*)(ws + 83361792);    //  [8][16][768]
    float*  carr   = (float*)(ws + 83755008);    //  [8][16][768]
    float*  x1     = (float*)(ws + 84148224);    //  [4096][768] fp32
    // total = 96,731,136 bytes

    // 1) weights -> bf16
    const int n768 = 768 * 768 / 4;        // 147456 vec4
    const int nbig = 3072 * 768 / 4;       // 589824 vec4
    k_cvt_bf16<<<dim3(n768 / 256), dim3(256), 0, stream>>>(Wr, wcat + 0 * 589824, n768);
    k_cvt_bf16<<<dim3(n768 / 256), dim3(256), 0, stream>>>(Wk, wcat + 1 * 589824, n768);
    k_cvt_bf16<<<dim3(n768 / 256), dim3(256), 0, stream>>>(Wv, wcat + 2 * 589824, n768);
    k_cvt_bf16<<<dim3(n768 / 256), dim3(256), 0, stream>>>(Wrt, wcat + 3 * 589824, n768);
    k_cvt_bf16<<<dim3(nbig / 256), dim3(256), 0, stream>>>(Wck, wckb, nbig);
    k_cvt_bf16<<<dim3(nbig / 256), dim3(256), 0, stream>>>(Wcv, wcvb, nbig);

    // 2) LN1
    k_ln<<<dim3(4096), dim3(256), 0, stream>>>(x, ln1w, ln1b, xx, 768);

    // 3) fused r|k|v|router GEMM: y4 = xx @ wcat^T  (M=4096, N=3072, K=768)
    k_gemm_bt<0><<<dim3(24, 32), dim3(256), 0, stream>>>(xx, wcat, (void*)y4, nullptr, 3072, 768);

    // 4) wkv scan + mix -> x1
    k_scan_local<<<dim3(384), dim3(256), 0, stream>>>(y4, tmw, wkvl, states);
    k_scan_carry<<<dim3(24), dim3(256), 0, stream>>>(states, tmw, carr);
    k_mix<<<dim3(3072), dim3(256), 0, stream>>>(y4, wkvl, carr, tmw, x, x1);

    // 5) LN2 (reuse xx buffer)
    k_ln<<<dim3(4096), dim3(256), 0, stream>>>(x1, ln2w, ln2b, xx, 768);

    // 6) k_cm = bf16(relu(xx2 @ Wck^T)^2)  (M=4096, N=3072, K=768)
    k_gemm_bt<1><<<dim3(24, 32), dim3(256), 0, stream>>>(xx, wckb, (void*)kcm, nullptr, 3072, 768);

    // 7) out = x1 + k_cm @ Wcv^T  (M=4096, N=768, K=3072)
    k_gemm_bt<2><<<dim3(6, 32), dim3(256), 0, stream>>>(kcm, wcvb, (void*)out, x1, 768, 3072);
}

// Round 2
// 175.701 us; speedup vs baseline: 1.1446x; 1.1446x over previous
//
#include <hip/hip_runtime.h>
#include <hip/hip_bf16.h>

typedef __bf16 bf16_t;
typedef __bf16 bf16x8 __attribute__((ext_vector_type(8)));
typedef __bf16 bf16x4 __attribute__((ext_vector_type(4)));
typedef float  f32x4  __attribute__((ext_vector_type(4)));

#define LN_EPS 1e-5f

// B=8, T=512, C=768 -> M = 4096, 4C = 3072

// ---------------- async global->LDS helper (16B per lane, wave-uniform LDS base) ----
typedef __attribute__((address_space(1))) void gvoid_t;
typedef __attribute__((address_space(3))) void lvoid_t;
__device__ __forceinline__ void glds16(const void* g, void* l) {
    __builtin_amdgcn_global_load_lds((gvoid_t*)g, (lvoid_t*)l, 16, 0, 0);
}

// ---------------- fp32 -> bf16 conversion, 4 equal-size square weights ----------------
__global__ __launch_bounds__(256) void k_cvt4(const float* __restrict__ s0,
                                              const float* __restrict__ s1,
                                              const float* __restrict__ s2,
                                              const float* __restrict__ s3,
                                              bf16_t* __restrict__ dst, int n4) {
    const float* s = (blockIdx.y == 0) ? s0 : (blockIdx.y == 1) ? s1 : (blockIdx.y == 2) ? s2 : s3;
    bf16_t* d = dst + (size_t)blockIdx.y * ((size_t)n4 * 4);
    int i = blockIdx.x * 256 + threadIdx.x;
    if (i < n4) {
        float4 v = ((const float4*)s)[i];
        bf16x4 o;
        o.x = (bf16_t)v.x; o.y = (bf16_t)v.y; o.z = (bf16_t)v.z; o.w = (bf16_t)v.w;
        ((bf16x4*)d)[i] = o;
    }
}

__global__ __launch_bounds__(256) void k_cvt2(const float* __restrict__ s0,
                                              const float* __restrict__ s1,
                                              bf16_t* __restrict__ dst, int n4) {
    const float* s = (blockIdx.y == 0) ? s0 : s1;
    bf16_t* d = dst + (size_t)blockIdx.y * ((size_t)n4 * 4);
    int i = blockIdx.x * 256 + threadIdx.x;
    if (i < n4) {
        float4 v = ((const float4*)s)[i];
        bf16x4 o;
        o.x = (bf16_t)v.x; o.y = (bf16_t)v.y; o.z = (bf16_t)v.z; o.w = (bf16_t)v.w;
        ((bf16x4*)d)[i] = o;
    }
}

// ---------------- LayerNorm (one block per row of C=768), bf16 out ----------------
__global__ __launch_bounds__(256) void k_ln(const float* __restrict__ x,
                                            const float* __restrict__ w,
                                            const float* __restrict__ b,
                                            bf16_t* __restrict__ out, int C) {
    int row = blockIdx.x;
    const float* xr = x + (long)row * C;
    int tid = threadIdx.x;
    float s = 0.f, s2 = 0.f;
    for (int i = tid; i < C; i += 256) { float v = xr[i]; s += v; s2 += v * v; }
    for (int m = 32; m; m >>= 1) { s += __shfl_xor(s, m, 64); s2 += __shfl_xor(s2, m, 64); }
    __shared__ float red[8];
    int wv = tid >> 6;
    if ((tid & 63) == 0) { red[wv] = s; red[4 + wv] = s2; }
    __syncthreads();
    float ts  = red[0] + red[1] + red[2] + red[3];
    float ts2 = red[4] + red[5] + red[6] + red[7];
    float mu  = ts / C;
    float var = ts2 / C - mu * mu;
    float rstd = rsqrtf(var + LN_EPS);
    bf16_t* orow = out + (long)row * C;
    for (int i = tid; i < C; i += 256)
        orow[i] = (bf16_t)((xr[i] - mu) * rstd * w[i] + b[i]);
}

// ---------------- bf16 MFMA GEMM (m97 structure):  C[M][N] = A[M][K] * Bw[N][K]^T ----
// 128x128 tile, 4 waves (2x2 of 64x64), 16x16x32 bf16 MFMA, BK=32,
// global_load_lds dwordx4 staging into LINEAR (unpadded) LDS.
// EPI 0: store bf16      EPI 1: store bf16(relu(x)^2)      EPI 2: store fp32 aux+val
template <int EPI>
__global__ __launch_bounds__(256) void k_gemm_bt(const bf16_t* __restrict__ A,
                                                 const bf16_t* __restrict__ Bw,
                                                 void* __restrict__ Cout,
                                                 const float* __restrict__ aux,
                                                 int N, int K, int nbn) {
    __shared__ __align__(16) bf16_t As[128][32];   // linear: required by global_load_lds
    __shared__ __align__(16) bf16_t Bs[128][32];
    const int tid  = threadIdx.x;
    const int lane = tid & 63, wid = tid >> 6;
    const int wm = (wid >> 1) * 64, wn = (wid & 1) * 64;

    // XCD-aware swizzle (gridDim.x % 8 == 0 for all our launches)
    int nwg = gridDim.x;
    int cpx = nwg >> 3;
    int bid = blockIdx.x;
    int swz = (bid & 7) * cpx + (bid >> 3);
    int bm = swz / nbn, bn = swz % nbn;

    const int fr = lane & 15, ko = (lane >> 4) * 8;  // fragment row / k-octet

    f32x4 acc[4][4];
#pragma unroll
    for (int i = 0; i < 4; i++)
#pragma unroll
        for (int j = 0; j < 4; j++) acc[i][j] = (f32x4){0.f, 0.f, 0.f, 0.f};

    // staging: wave w owns rows [w*32, w*32+32); lane covers (row = base + lane/4, col8 = lane%4)
    const int srow = wid * 32 + (lane >> 2);
    const int scol = (lane & 3) * 8;
    const bf16_t* Ag = A  + (size_t)(bm * 128 + srow) * K + scol;
    const bf16_t* Bg = Bw + (size_t)(bn * 128 + srow) * K + scol;
    const size_t rowK16 = (size_t)16 * K;
    bf16_t* lA0 = &As[wid * 32][0];
    bf16_t* lA1 = &As[wid * 32 + 16][0];
    bf16_t* lB0 = &Bs[wid * 32][0];
    bf16_t* lB1 = &Bs[wid * 32 + 16][0];

    for (int kt = 0; kt < K; kt += 32) {
        glds16(Ag + kt,          lA0);
        glds16(Ag + kt + rowK16, lA1);
        glds16(Bg + kt,          lB0);
        glds16(Bg + kt + rowK16, lB1);
        __syncthreads();          // drains vmcnt -> LDS tile valid
        bf16x8 af[4], bfr[4];
#pragma unroll
        for (int mi = 0; mi < 4; mi++) af[mi]  = *(const bf16x8*)&As[wm + mi * 16 + fr][ko];
#pragma unroll
        for (int ni = 0; ni < 4; ni++) bfr[ni] = *(const bf16x8*)&Bs[wn + ni * 16 + fr][ko];
#pragma unroll
        for (int mi = 0; mi < 4; mi++)
#pragma unroll
            for (int ni = 0; ni < 4; ni++)
                acc[mi][ni] = __builtin_amdgcn_mfma_f32_16x16x32_bf16(af[mi], bfr[ni], acc[mi][ni], 0, 0, 0);
        __syncthreads();          // all reads done before next overwrite
    }

    const int row0 = bm * 128 + wm, col0 = bn * 128 + wn;
#pragma unroll
    for (int mi = 0; mi < 4; mi++) {
#pragma unroll
        for (int ni = 0; ni < 4; ni++) {
            int row = row0 + mi * 16 + (lane >> 4) * 4;   // C/D: col=lane&15, row=(lane>>4)*4+r
            int col = col0 + ni * 16 + (lane & 15);
#pragma unroll
            for (int r = 0; r < 4; r++) {
                float val = acc[mi][ni][r];
                size_t off = (size_t)(row + r) * N + col;
                if (EPI == 0) {
                    ((bf16_t*)Cout)[off] = (bf16_t)val;
                } else if (EPI == 1) {
                    float t = fmaxf(val, 0.f);
                    ((bf16_t*)Cout)[off] = (bf16_t)(t * t);
                } else {
                    ((float*)Cout)[off] = aux[off] + val;
                }
            }
        }
    }
}

// ---------------- WKV chunked scan (y4 now bf16) ----------------
// y4 layout per (b,t): [ r(768) | k(768) | v(768) | router(768) ]
__global__ __launch_bounds__(256) void k_scan_local(const bf16_t* __restrict__ y4,
                                                    const float* __restrict__ tmw,
                                                    float* __restrict__ wkvl,
                                                    float* __restrict__ states) {
    int idx = blockIdx.x * 256 + threadIdx.x;  // (b*16 + ch)*768 + c ; total 8*16*768
    int c   = idx % 768;
    int rem = idx / 768;
    int ch  = rem & 15;
    int b   = rem >> 4;
    float d = expf(-expf(tmw[c]));
    const bf16_t* base = y4 + ((size_t)(b * 512 + ch * 32)) * 3072 + c;
    float*        wout = wkvl + ((size_t)(b * 512 + ch * 32)) * 768 + c;
    float s = 0.f;
#pragma unroll 4
    for (int i = 0; i < 32; i++) {
        float kk = (float)base[(size_t)i * 3072 + 768];
        float vv = (float)base[(size_t)i * 3072 + 1536];
        s = s * d + kk * vv;
        wout[(size_t)i * 768] = s;
    }
    states[idx] = s;
}

__global__ __launch_bounds__(256) void k_scan_carry(const float* __restrict__ states,
                                                    const float* __restrict__ tmw,
                                                    float* __restrict__ carries) {
    int idx = blockIdx.x * 256 + threadIdx.x;  // b*768 + c ; total 8*768
    int c = idx % 768, b = idx / 768;
    float dL = expf(-expf(tmw[c]) * 32.f);
    float s = 0.f;
    for (int ch = 0; ch < 16; ch++) {
        size_t o = ((size_t)(b * 16 + ch)) * 768 + c;
        carries[o] = s;
        s = s * dL + states[o];
    }
}

// ---------------- mix + LN2 fused: one block per (b,t) row ----------------
// x1 = x + r * ((wkv_local + carry*d^(tmod+1)) * sigmoid(router));  xx2 = LN2(x1) bf16
__global__ __launch_bounds__(256) void k_mix_ln(const bf16_t* __restrict__ y4,
                                                const float* __restrict__ wkvl,
                                                const float* __restrict__ carries,
                                                const float* __restrict__ tmw,
                                                const float* __restrict__ x,
                                                const float* __restrict__ w2,
                                                const float* __restrict__ b2,
                                                float* __restrict__ x1,
                                                bf16_t* __restrict__ xx2) {
    int bt = blockIdx.x;
    int t = bt & 511, b = bt >> 9;
    int tid = threadIdx.x;
    const bf16_t* yrow = y4 + (size_t)bt * 3072;
    const float*  wl   = wkvl + (size_t)bt * 768;
    const float*  cr   = carries + ((size_t)(b * 16) + (t >> 5)) * 768;
    const float*  xr   = x + (size_t)bt * 768;
    float tn = (float)((t & 31) + 1);

    float vals[3];
    float s = 0.f, s2 = 0.f;
#pragma unroll
    for (int j = 0; j < 3; j++) {
        int c = tid + j * 256;
        float rr = (float)yrow[c];
        float gg = (float)yrow[c + 2304];
        float wk = wl[c] + cr[c] * expf(-expf(tmw[c]) * tn);
        float sig = 1.f / (1.f + expf(-gg));
        float o = fmaf(rr, wk * sig, xr[c]);
        vals[j] = o; s += o; s2 += o * o;
    }
    for (int m = 32; m; m >>= 1) { s += __shfl_xor(s, m, 64); s2 += __shfl_xor(s2, m, 64); }
    __shared__ float red[8];
    int wv = tid >> 6;
    if ((tid & 63) == 0) { red[wv] = s; red[4 + wv] = s2; }
    __syncthreads();
    float ts  = red[0] + red[1] + red[2] + red[3];
    float ts2 = red[4] + red[5] + red[6] + red[7];
    float mu  = ts * (1.f / 768.f);
    float var = ts2 * (1.f / 768.f) - mu * mu;
    float rstd = rsqrtf(var + LN_EPS);
    float* x1r = x1 + (size_t)bt * 768;
    bf16_t* xo = xx2 + (size_t)bt * 768;
#pragma unroll
    for (int j = 0; j < 3; j++) {
        int c = tid + j * 256;
        x1r[c] = vals[j];
        xo[c] = (bf16_t)((vals[j] - mu) * rstd * w2[c] + b2[c]);
    }
}

// ---------------- host-side launch ----------------
extern "C" void kernel_launch(void* const* d_in, const int* in_sizes, int n_in,
                              void* d_out, int out_size, void* d_ws, size_t ws_size,
                              hipStream_t stream) {
    const float* x    = (const float*)d_in[0];
    const float* ln1w = (const float*)d_in[1];
    const float* ln1b = (const float*)d_in[2];
    const float* Wr   = (const float*)d_in[3];
    const float* Wk   = (const float*)d_in[4];
    const float* Wv   = (const float*)d_in[5];
    const float* tmw  = (const float*)d_in[6];
    const float* Wrt  = (const float*)d_in[7];
    const float* ln2w = (const float*)d_in[8];
    const float* ln2b = (const float*)d_in[9];
    const float* Wck  = (const float*)d_in[10];
    const float* Wcv  = (const float*)d_in[11];
    float* out = (float*)d_out;
    char* ws = (char*)d_ws;

    // workspace layout (bytes) — total 96,731,136 (same footprint as round 1)
    bf16_t* xx     = (bf16_t*)(ws + 0);          // 4096*768 bf16 (xx, reused as xx2)
    bf16_t* wcat   = (bf16_t*)(ws + 6291456);    // [4][768][768] bf16 (r,k,v,router)
    bf16_t* wckb   = (bf16_t*)(ws + 11010048);   // [3072][768] bf16
    bf16_t* wcvb   = (bf16_t*)(ws + 15728640);   // [768][3072] bf16 (contiguous after wckb)
    bf16_t* y4     = (bf16_t*)(ws + 20447232);   // [4096][3072] bf16
    bf16_t* kcm    = (bf16_t*)(ws + 20447232);   // reuses y4 after mix
    float*  wkvl   = (float*)(ws + 70778880);    // [4096][768] fp32
    float*  states = (float*)(ws + 83361792);    // [8][16][768]
    float*  carr   = (float*)(ws + 83755008);    // [8][16][768]
    float*  x1     = (float*)(ws + 84148224);    // [4096][768] fp32

    // 1) weights -> bf16 (2 launches)
    const int n768 = 768 * 768 / 4;        // 147456 vec4
    const int nbig = 3072 * 768 / 4;       // 589824 vec4
    k_cvt4<<<dim3(576, 4), dim3(256), 0, stream>>>(Wr, Wk, Wv, Wrt, wcat, n768);
    k_cvt2<<<dim3(2304, 2), dim3(256), 0, stream>>>(Wck, Wcv, wckb, nbig);

    // 2) LN1
    k_ln<<<dim3(4096), dim3(256), 0, stream>>>(x, ln1w, ln1b, xx, 768);

    // 3) fused r|k|v|router GEMM: y4 = xx @ wcat^T  (M=4096, N=3072, K=768), bf16 out
    k_gemm_bt<0><<<dim3(768), dim3(256), 0, stream>>>(xx, wcat, (void*)y4, nullptr, 3072, 768, 24);

    // 4) wkv scan + mix(+LN2) -> x1, xx2
    k_scan_local<<<dim3(384), dim3(256), 0, stream>>>(y4, tmw, wkvl, states);
    k_scan_carry<<<dim3(24), dim3(256), 0, stream>>>(states, tmw, carr);
    k_mix_ln<<<dim3(4096), dim3(256), 0, stream>>>(y4, wkvl, carr, tmw, x, ln2w, ln2b, x1, xx);

    // 5) k_cm = bf16(relu(xx2 @ Wck^T)^2)  (M=4096, N=3072, K=768)
    k_gemm_bt<1><<<dim3(768), dim3(256), 0, stream>>>(xx, wckb, (void*)kcm, nullptr, 3072, 768, 24);

    // 6) out = x1 + k_cm @ Wcv^T  (M=4096, N=768, K=3072)
    k_gemm_bt<2><<<dim3(192), dim3(256), 0, stream>>>(kcm, wcvb, (void*)out, x1, 768, 3072, 6);
}

// Round 3
// 158.418 us; speedup vs baseline: 1.2695x; 1.1091x over previous
//
#include <hip/hip_runtime.h>
#include <hip/hip_bf16.h>

typedef __bf16 bf16_t;
typedef __bf16 bf16x8 __attribute__((ext_vector_type(8)));
typedef __bf16 bf16x4 __attribute__((ext_vector_type(4)));
typedef float  f32x4  __attribute__((ext_vector_type(4)));

#define LN_EPS 1e-5f

// B=8, T=512, C=768 -> M = 4096, 4C = 3072

// ---------------- async global->LDS helper (16B per lane, wave-uniform LDS base) ----
typedef __attribute__((address_space(1))) void gvoid_t;
typedef __attribute__((address_space(3))) void lvoid_t;
__device__ __forceinline__ void glds16(const void* g, void* l) {
    __builtin_amdgcn_global_load_lds((gvoid_t*)g, (lvoid_t*)l, 16, 0, 0);
}

// ---------------- fp32 -> bf16 conversion ----------------
__global__ __launch_bounds__(256) void k_cvt4(const float* __restrict__ s0,
                                              const float* __restrict__ s1,
                                              const float* __restrict__ s2,
                                              const float* __restrict__ s3,
                                              bf16_t* __restrict__ dst, int n4) {
    const float* s = (blockIdx.y == 0) ? s0 : (blockIdx.y == 1) ? s1 : (blockIdx.y == 2) ? s2 : s3;
    bf16_t* d = dst + (size_t)blockIdx.y * ((size_t)n4 * 4);
    int i = blockIdx.x * 256 + threadIdx.x;
    if (i < n4) {
        float4 v = ((const float4*)s)[i];
        bf16x4 o;
        o.x = (bf16_t)v.x; o.y = (bf16_t)v.y; o.z = (bf16_t)v.z; o.w = (bf16_t)v.w;
        ((bf16x4*)d)[i] = o;
    }
}

__global__ __launch_bounds__(256) void k_cvt2(const float* __restrict__ s0,
                                              const float* __restrict__ s1,
                                              bf16_t* __restrict__ dst, int n4) {
    const float* s = (blockIdx.y == 0) ? s0 : s1;
    bf16_t* d = dst + (size_t)blockIdx.y * ((size_t)n4 * 4);
    int i = blockIdx.x * 256 + threadIdx.x;
    if (i < n4) {
        float4 v = ((const float4*)s)[i];
        bf16x4 o;
        o.x = (bf16_t)v.x; o.y = (bf16_t)v.y; o.z = (bf16_t)v.z; o.w = (bf16_t)v.w;
        ((bf16x4*)d)[i] = o;
    }
}

// ---------------- LayerNorm (one block per row of C=768), bf16 out ----------------
__global__ __launch_bounds__(256) void k_ln(const float* __restrict__ x,
                                            const float* __restrict__ w,
                                            const float* __restrict__ b,
                                            bf16_t* __restrict__ out, int C) {
    int row = blockIdx.x;
    const float* xr = x + (long)row * C;
    int tid = threadIdx.x;
    float s = 0.f, s2 = 0.f;
    for (int i = tid; i < C; i += 256) { float v = xr[i]; s += v; s2 += v * v; }
    for (int m = 32; m; m >>= 1) { s += __shfl_xor(s, m, 64); s2 += __shfl_xor(s2, m, 64); }
    __shared__ float red[8];
    int wv = tid >> 6;
    if ((tid & 63) == 0) { red[wv] = s; red[4 + wv] = s2; }
    __syncthreads();
    float ts  = red[0] + red[1] + red[2] + red[3];
    float ts2 = red[4] + red[5] + red[6] + red[7];
    float mu  = ts / C;
    float var = ts2 / C - mu * mu;
    float rstd = rsqrtf(var + LN_EPS);
    bf16_t* orow = out + (long)row * C;
    for (int i = tid; i < C; i += 256)
        orow[i] = (bf16_t)((xr[i] - mu) * rstd * w[i] + b[i]);
}

// ---------------- bf16 MFMA GEMM, double-buffered:  C[M][N] = A[M][K] * Bw[N][K]^T ---
// Tile 128 x BN (BN=128 or 64), 4 waves, 16x16x32 bf16 MFMA, BK=32.
// 2-phase pipeline: issue next tile's global_load_lds BEFORE compute of current tile;
// single __syncthreads() per iter (its vmcnt drain pays only residual latency).
// EPI 0: store bf16      EPI 1: store bf16(relu(x)^2)      EPI 2: store fp32 aux+val
template <int EPI, int BN>
__global__ __launch_bounds__(256) void k_gemm_bt(const bf16_t* __restrict__ A,
                                                 const bf16_t* __restrict__ Bw,
                                                 void* __restrict__ Cout,
                                                 const float* __restrict__ aux,
                                                 int N, int K, int nbn) {
    constexpr int NI = BN / 32;          // accum tiles per wave in N (4 or 2)
    constexpr int WN = BN / 2;           // wave N-extent (64 or 32)
    constexpr int ABUF = 128 * 32;       // elements per A buffer
    constexpr int BBUF = BN * 32;        // elements per B buffer
    __shared__ __align__(16) bf16_t As[2][128][32];   // linear (global_load_lds dest)
    __shared__ __align__(16) bf16_t Bs[2][BN][32];

    const int tid  = threadIdx.x;
    const int lane = tid & 63, wid = tid >> 6;
    const int wm = (wid >> 1) * 64, wn = (wid & 1) * WN;

    // XCD-aware swizzle (nwg % 8 == 0 for all launches here)
    int nwg = gridDim.x;
    int cpx = nwg >> 3;
    int bid = blockIdx.x;
    int swz = (bid & 7) * cpx + (bid >> 3);
    int bm = swz / nbn, bn = swz % nbn;

    const int fr = lane & 15, ko = (lane >> 4) * 8;  // fragment row / k-octet

    f32x4 acc[4][NI];
#pragma unroll
    for (int i = 0; i < 4; i++)
#pragma unroll
        for (int j = 0; j < NI; j++) acc[i][j] = (f32x4){0.f, 0.f, 0.f, 0.f};

    // staging: one glds16 per wave covers 16 rows x 32 cols; lane l -> row +l/4, col8 l%4
    const int srow = wid * 16 + (lane >> 2);
    const int scol = (lane & 3) * 8;
    const bf16_t* Ag = A  + (size_t)(bm * 128 + srow) * K + scol;
    const bf16_t* Bg = Bw + (size_t)(bn * BN + srow) * K + scol;
    const size_t rowK64 = (size_t)64 * K;
    bf16_t* lA = &As[0][wid * 16][0];    // wave-uniform LDS bases
    bf16_t* lB = &Bs[0][wid * 16][0];

#define STAGE(buf, kt)                                                          \
    do {                                                                        \
        glds16(Ag + (kt),          lA + (buf) * ABUF);                          \
        glds16(Ag + (kt) + rowK64, lA + (buf) * ABUF + 64 * 32);                \
        glds16(Bg + (kt),          lB + (buf) * BBUF);                          \
        if (BN == 128) glds16(Bg + (kt) + rowK64, lB + (buf) * BBUF + 64 * 32); \
    } while (0)

#define COMPUTE(buf)                                                                         \
    do {                                                                                     \
        bf16x8 af[4], bfr[NI];                                                               \
        _Pragma("unroll")                                                                    \
        for (int mi = 0; mi < 4; mi++) af[mi] = *(const bf16x8*)&As[buf][wm + mi * 16 + fr][ko]; \
        _Pragma("unroll")                                                                    \
        for (int ni = 0; ni < NI; ni++) bfr[ni] = *(const bf16x8*)&Bs[buf][wn + ni * 16 + fr][ko]; \
        _Pragma("unroll")                                                                    \
        for (int mi = 0; mi < 4; mi++)                                                       \
            _Pragma("unroll")                                                                \
            for (int ni = 0; ni < NI; ni++)                                                  \
                acc[mi][ni] = __builtin_amdgcn_mfma_f32_16x16x32_bf16(af[mi], bfr[ni], acc[mi][ni], 0, 0, 0); \
    } while (0)

    STAGE(0, 0);
    __syncthreads();                 // prologue drain: buf0 valid
    int cur = 0;
    for (int kt = 0; kt < K - 32; kt += 32) {
        STAGE(cur ^ 1, kt + 32);     // prefetch next tile (latency hides under compute)
        COMPUTE(cur);
        __syncthreads();             // drains vmcnt (next tile landed) + all reads done
        cur ^= 1;
    }
    COMPUTE(cur);                    // last tile

#undef STAGE
#undef COMPUTE

    const int row0 = bm * 128 + wm, col0 = bn * BN + wn;
#pragma unroll
    for (int mi = 0; mi < 4; mi++) {
#pragma unroll
        for (int ni = 0; ni < NI; ni++) {
            int row = row0 + mi * 16 + (lane >> 4) * 4;   // C/D: col=lane&15, row=(lane>>4)*4+r
            int col = col0 + ni * 16 + (lane & 15);
#pragma unroll
            for (int r = 0; r < 4; r++) {
                float val = acc[mi][ni][r];
                size_t off = (size_t)(row + r) * N + col;
                if (EPI == 0) {
                    ((bf16_t*)Cout)[off] = (bf16_t)val;
                } else if (EPI == 1) {
                    float t = fmaxf(val, 0.f);
                    ((bf16_t*)Cout)[off] = (bf16_t)(t * t);
                } else {
                    ((float*)Cout)[off] = aux[off] + val;
                }
            }
        }
    }
}

// ---------------- WKV chunked scan (y4 bf16) ----------------
// y4 layout per (b,t): [ r(768) | k(768) | v(768) | router(768) ]
__global__ __launch_bounds__(256) void k_scan_local(const bf16_t* __restrict__ y4,
                                                    const float* __restrict__ tmw,
                                                    float* __restrict__ wkvl,
                                                    float* __restrict__ states) {
    int idx = blockIdx.x * 256 + threadIdx.x;  // (b*16 + ch)*768 + c
    int c   = idx % 768;
    int rem = idx / 768;
    int ch  = rem & 15;
    int b   = rem >> 4;
    float d = expf(-expf(tmw[c]));
    const bf16_t* base = y4 + ((size_t)(b * 512 + ch * 32)) * 3072 + c;
    float*        wout = wkvl + ((size_t)(b * 512 + ch * 32)) * 768 + c;
    float s = 0.f;
#pragma unroll 4
    for (int i = 0; i < 32; i++) {
        float kk = (float)base[(size_t)i * 3072 + 768];
        float vv = (float)base[(size_t)i * 3072 + 1536];
        s = s * d + kk * vv;
        wout[(size_t)i * 768] = s;
    }
    states[idx] = s;
}

__global__ __launch_bounds__(256) void k_scan_carry(const float* __restrict__ states,
                                                    const float* __restrict__ tmw,
                                                    float* __restrict__ carries) {
    int idx = blockIdx.x * 256 + threadIdx.x;  // b*768 + c
    int c = idx % 768, b = idx / 768;
    float dL = expf(-expf(tmw[c]) * 32.f);
    float s = 0.f;
    for (int ch = 0; ch < 16; ch++) {
        size_t o = ((size_t)(b * 16 + ch)) * 768 + c;
        carries[o] = s;
        s = s * dL + states[o];
    }
}

// ---------------- mix + LN2 fused: one block per (b,t) row ----------------
__global__ __launch_bounds__(256) void k_mix_ln(const bf16_t* __restrict__ y4,
                                                const float* __restrict__ wkvl,
                                                const float* __restrict__ carries,
                                                const float* __restrict__ tmw,
                                                const float* __restrict__ x,
                                                const float* __restrict__ w2,
                                                const float* __restrict__ b2,
                                                float* __restrict__ x1,
                                                bf16_t* __restrict__ xx2) {
    int bt = blockIdx.x;
    int t = bt & 511, b = bt >> 9;
    int tid = threadIdx.x;
    const bf16_t* yrow = y4 + (size_t)bt * 3072;
    const float*  wl   = wkvl + (size_t)bt * 768;
    const float*  cr   = carries + ((size_t)(b * 16) + (t >> 5)) * 768;
    const float*  xr   = x + (size_t)bt * 768;
    float tn = (float)((t & 31) + 1);

    float vals[3];
    float s = 0.f, s2 = 0.f;
#pragma unroll
    for (int j = 0; j < 3; j++) {
        int c = tid + j * 256;
        float rr = (float)yrow[c];
        float gg = (float)yrow[c + 2304];
        float wk = wl[c] + cr[c] * expf(-expf(tmw[c]) * tn);
        float sig = 1.f / (1.f + expf(-gg));
        float o = fmaf(rr, wk * sig, xr[c]);
        vals[j] = o; s += o; s2 += o * o;
    }
    for (int m = 32; m; m >>= 1) { s += __shfl_xor(s, m, 64); s2 += __shfl_xor(s2, m, 64); }
    __shared__ float red[8];
    int wv = tid >> 6;
    if ((tid & 63) == 0) { red[wv] = s; red[4 + wv] = s2; }
    __syncthreads();
    float ts  = red[0] + red[1] + red[2] + red[3];
    float ts2 = red[4] + red[5] + red[6] + red[7];
    float mu  = ts * (1.f / 768.f);
    float var = ts2 * (1.f / 768.f) - mu * mu;
    float rstd = rsqrtf(var + LN_EPS);
    float* x1r = x1 + (size_t)bt * 768;
    bf16_t* xo = xx2 + (size_t)bt * 768;
#pragma unroll
    for (int j = 0; j < 3; j++) {
        int c = tid + j * 256;
        x1r[c] = vals[j];
        xo[c] = (bf16_t)((vals[j] - mu) * rstd * w2[c] + b2[c]);
    }
}

// ---------------- host-side launch ----------------
extern "C" void kernel_launch(void* const* d_in, const int* in_sizes, int n_in,
                              void* d_out, int out_size, void* d_ws, size_t ws_size,
                              hipStream_t stream) {
    const float* x    = (const float*)d_in[0];
    const float* ln1w = (const float*)d_in[1];
    const float* ln1b = (const float*)d_in[2];
    const float* Wr   = (const float*)d_in[3];
    const float* Wk   = (const float*)d_in[4];
    const float* Wv   = (const float*)d_in[5];
    const float* tmw  = (const float*)d_in[6];
    const float* Wrt  = (const float*)d_in[7];
    const float* ln2w = (const float*)d_in[8];
    const float* ln2b = (const float*)d_in[9];
    const float* Wck  = (const float*)d_in[10];
    const float* Wcv  = (const float*)d_in[11];
    float* out = (float*)d_out;
    char* ws = (char*)d_ws;

    // workspace layout (bytes)
    bf16_t* xx     = (bf16_t*)(ws + 0);          // 4096*768 bf16 (xx, reused as xx2)
    bf16_t* wcat   = (bf16_t*)(ws + 6291456);    // [4][768][768] bf16 (r,k,v,router)
    bf16_t* wckb   = (bf16_t*)(ws + 11010048);   // [3072][768] bf16
    bf16_t* wcvb   = (bf16_t*)(ws + 15728640);   // [768][3072] bf16
    bf16_t* y4     = (bf16_t*)(ws + 20447232);   // [4096][3072] bf16
    bf16_t* kcm    = (bf16_t*)(ws + 20447232);   // reuses y4 after mix
    float*  wkvl   = (float*)(ws + 70778880);    // [4096][768] fp32
    float*  states = (float*)(ws + 83361792);    // [8][16][768]
    float*  carr   = (float*)(ws + 83755008);    // [8][16][768]
    float*  x1     = (float*)(ws + 84148224);    // [4096][768] fp32

    // 1) weights -> bf16
    const int n768 = 768 * 768 / 4;
    const int nbig = 3072 * 768 / 4;
    k_cvt4<<<dim3(576, 4), dim3(256), 0, stream>>>(Wr, Wk, Wv, Wrt, wcat, n768);
    k_cvt2<<<dim3(2304, 2), dim3(256), 0, stream>>>(Wck, Wcv, wckb, nbig);

    // 2) LN1
    k_ln<<<dim3(4096), dim3(256), 0, stream>>>(x, ln1w, ln1b, xx, 768);

    // 3) fused r|k|v|router GEMM: y4 = xx @ wcat^T  (M=4096, N=3072, K=768), bf16 out
    k_gemm_bt<0, 128><<<dim3(768), dim3(256), 0, stream>>>(xx, wcat, (void*)y4, nullptr, 3072, 768, 24);

    // 4) wkv scan + mix(+LN2) -> x1, xx2
    k_scan_local<<<dim3(384), dim3(256), 0, stream>>>(y4, tmw, wkvl, states);
    k_scan_carry<<<dim3(24), dim3(256), 0, stream>>>(states, tmw, carr);
    k_mix_ln<<<dim3(4096), dim3(256), 0, stream>>>(y4, wkvl, carr, tmw, x, ln2w, ln2b, x1, xx);

    // 5) k_cm = bf16(relu(xx2 @ Wck^T)^2)  (M=4096, N=3072, K=768)
    k_gemm_bt<1, 128><<<dim3(768), dim3(256), 0, stream>>>(xx, wckb, (void*)kcm, nullptr, 3072, 768, 24);

    // 6) out = x1 + k_cm @ Wcv^T  (M=4096, N=768, K=3072) — BN=64: 384 blocks (1.5/CU)
    k_gemm_bt<2, 64><<<dim3(384), dim3(256), 0, stream>>>(kcm, wcvb, (void*)out, x1, 768, 3072, 12);
}